// Round 13
// baseline (901.293 us; speedup 1.0000x reference)
//
#include <hip/hip_runtime.h>

#define DIM 384
#define HEADS 12
#define HD 32
#define NTOK 49
#define NWIN 4096
#define MTOT (NWIN*NTOK)   // 200704 = 3136 * 64
#define PSTR 72            // padded LDS row stride (elements) for P and V^T

typedef __attribute__((ext_vector_type(8))) __bf16 bf16x8;
typedef __attribute__((ext_vector_type(4))) __bf16 bf16x4;
typedef __attribute__((ext_vector_type(4))) float f32x4;

static __device__ __forceinline__ f32x4 mfma16(bf16x8 a, bf16x8 b, f32x4 c) {
  return __builtin_amdgcn_mfma_f32_16x16x32_bf16(a, b, c, 0, 0, 0);
}

// async global->LDS, 16B per lane: dest = lds_base(wave-uniform) + lane*16
static __device__ __forceinline__ void gload_lds16(const void* g, void* l) {
  __builtin_amdgcn_global_load_lds(
      (const __attribute__((address_space(1))) unsigned int*)g,
      (__attribute__((address_space(3))) unsigned int*)l, 16, 0, 0);
}

static __device__ __forceinline__ bf16x4 cvt4(float4 v) {
  bf16x4 t;
  t[0]=(__bf16)v.x; t[1]=(__bf16)v.y; t[2]=(__bf16)v.z; t[3]=(__bf16)v.w;
  return t;
}

// ---------------- prep: weights -> bf16, bias table expand ----------------
__global__ void k_prep(const float* __restrict__ qw, const float* __restrict__ kvw,
                       const float* __restrict__ pw, const float* __restrict__ rel_table,
                       const int* __restrict__ rel_index,
                       __bf16* __restrict__ qw_bf, __bf16* __restrict__ kvw_bf,
                       __bf16* __restrict__ pw_bf, float* __restrict__ bias_pad) {
  int i = blockIdx.x * 256 + threadIdx.x;
  if (i < DIM*DIM)   qw_bf[i] = (__bf16)qw[i];
  if (i < 2*DIM*DIM) kvw_bf[i] = (__bf16)kvw[i];
  if (i < DIM*DIM)   pw_bf[i] = (__bf16)pw[i];
  if (i < HEADS*64*64) {
    int h = i >> 12, rem = i & 4095, q = rem >> 6, k = rem & 63;
    float v;
    if (k >= NTOK)      v = -1e30f;   // key padding: masks softmax for free
    else if (q >= NTOK) v = 0.0f;     // query padding rows are discarded
    else v = rel_table[rel_index[q*NTOK + k] * HEADS + h];
    bias_pad[i] = v;
  }
}

// ---------------- QKV GEMM v2 (race-fixed): A resident in LDS ---------------
// Block = 64-row M-tile x all N-chunks of one weight matrix (b even: x@qw -> Q;
// b odd: y@kvw -> K,V). A staged to LDS ONCE in prologue. Inner iteration:
//   vmcnt(counted) -> s_barrier -> ds_read tile kt -> gload tile kt+2 -> MFMA
// The barrier follows every wave's counted wait, so when it releases ALL
// waves' tile-kt loads have landed (the round-6 handshake — vmcnt is per-wave).
__global__ __launch_bounds__(256, 2) void k_qkv2(
    const float* __restrict__ x, const float* __restrict__ y,
    const __bf16* __restrict__ qw_bf, const __bf16* __restrict__ kvw_bf,
    const float* __restrict__ q_b, const float* __restrict__ kv_b,
    __bf16* __restrict__ Qws, __bf16* __restrict__ Kws, __bf16* __restrict__ Vws)
{
  __shared__ __align__(16) __bf16 Asub[12*64*32];   // 48 KB, 12 sub-tiles
  __shared__ __align__(16) __bf16 Bs[3*128*32];     // 24 KB ring

  const int b = blockIdx.x;
  const int type = b & 1;            // 0: Q from x, 1: KV from y
  const int mtile = b >> 1;
  const float* A = type ? y : x;
  const __bf16* Bw = type ? kvw_bf : qw_bf;
  const int NCH = type ? 6 : 3;
  const int row0b = mtile * 64;

  const int t = threadIdx.x, lane = t & 63, wave = t >> 6;   // 4 waves
  const int l15 = lane & 15, g = lane >> 4;
  const int wm = wave >> 1, wn = wave & 1;

  // ---- A staging (prologue only): u0 rows wave*8+r8 (0..31), u1 +32 ----
  {
    const int c8 = lane & 7, r8 = lane >> 3;
    const int swk = (lane >> 4) & 3;             // == (row>>1)&3 for u0 and u1
    const float* asrc = A + (size_t)(row0b + wave*8 + r8)*DIM + c8*4;
    const unsigned lwA = (unsigned)(wave*8 + r8)*64
                       + ((((c8 >> 1) ^ swk) << 4) + (c8 & 1)*8);
    #pragma unroll
    for (int st = 0; st < 12; ++st) {
      float4 u0 = *(const float4*)(asrc + st*32);
      float4 u1 = *(const float4*)(asrc + st*32 + 32*DIM);
      *(bf16x4*)((char*)Asub + st*4096 + lwA)        = cvt4(u0);
      *(bf16x4*)((char*)Asub + st*4096 + 2048 + lwA) = cvt4(u1);  // row+32
    }
  }

  // ---- B staging pointers (pre-swizzled source, proven mapping) ----
  const int sr  = 2*(lane >> 3) + ((lane >> 2) & 1);
  const int scb = (lane & 3) ^ ((lane >> 3) & 3);
  const __bf16* bsrc0 = Bw + (size_t)((wave*2    )*16 + sr)*DIM + scb*8;
  const __bf16* bsrc1 = Bw + (size_t)((wave*2 + 1)*16 + sr)*DIM + scb*8;

  // prologue: issue B tiles 0 and 1 of chunk 0
  gload_lds16(bsrc0,      (char*)Bs        + (wave*2  )*1024);
  gload_lds16(bsrc1,      (char*)Bs        + (wave*2+1)*1024);
  gload_lds16(bsrc0 + 32, (char*)Bs + 8192 + (wave*2  )*1024);
  gload_lds16(bsrc1 + 32, (char*)Bs + 8192 + (wave*2+1)*1024);
  asm volatile("s_waitcnt lgkmcnt(0)" ::: "memory");  // A ds_writes drained
  __builtin_amdgcn_s_barrier();                       // Asub visible to all

  const int lslot = l15*64 + ((g ^ ((l15 >> 1) & 3)) << 4);

  for (int jn = 0; jn < NCH; ++jn) {
    const size_t co = (size_t)jn * 49152;     // jn*128*DIM
    const size_t cn = co + 49152;
    f32x4 acc[2][4];
    #pragma unroll
    for (int a=0;a<2;a++)
      #pragma unroll
      for (int bb=0;bb<4;bb++) acc[a][bb] = (f32x4){0.f,0.f,0.f,0.f};

    #pragma unroll
    for (int kt = 0; kt < 12; ++kt) {
      // counted wait FIRST (my tile-kt loads landed), THEN barrier:
      // when it releases, ALL waves' tile-kt loads have landed.
      if (kt == 11 && jn == NCH-1) asm volatile("s_waitcnt vmcnt(0)" ::: "memory");
      else                         asm volatile("s_waitcnt vmcnt(2)" ::: "memory");
      __builtin_amdgcn_s_barrier();

      const int cb = kt % 3;
      bf16x8 af[2], bfv[4];
      af[0] = *(const bf16x8*)((const char*)Asub + kt*4096 + (wm*32     )*64 + lslot);
      af[1] = *(const bf16x8*)((const char*)Asub + kt*4096 + (wm*32 + 16)*64 + lslot);
      #pragma unroll
      for (int bb=0;bb<4;bb++)
        bfv[bb] = *(const bf16x8*)((const char*)Bs + cb*8192 + (wn*64 + bb*16)*64 + lslot);

      // issue tile kt+2 into slot (kt+2)%3 == (kt-1)%3: its readers finished
      // (consumed by MFMA(kt-1)) before any wave reached the barrier above.
      if (kt < 10) {
        gload_lds16(bsrc0 + co + (kt+2)*32, (char*)Bs + ((kt+2)%3)*8192 + (wave*2  )*1024);
        gload_lds16(bsrc1 + co + (kt+2)*32, (char*)Bs + ((kt+2)%3)*8192 + (wave*2+1)*1024);
      } else if (jn < NCH-1) {
        const int k2 = kt - 10;               // next chunk tiles 0,1
        gload_lds16(bsrc0 + cn + k2*32, (char*)Bs + ((kt+2)%3)*8192 + (wave*2  )*1024);
        gload_lds16(bsrc1 + cn + k2*32, (char*)Bs + ((kt+2)%3)*8192 + (wave*2+1)*1024);
      }

      #pragma unroll
      for (int a=0;a<2;a++)
        #pragma unroll
        for (int bb=0;bb<4;bb++)
          acc[a][bb] = mfma16(af[a], bfv[bb], acc[a][bb]);
    }

    // ---- chunk epilogue ----
    const float* biasp = (type ? kv_b : q_b) + jn*128;
    __bf16* Cout; int col0;
    if (!type)        { Cout = Qws; col0 = jn*128; }
    else if (jn < 3)  { Cout = Kws; col0 = jn*128; }
    else              { Cout = Vws; col0 = (jn-3)*128; }
    #pragma unroll
    for (int a=0;a<2;a++) {
      #pragma unroll
      for (int bb=0;bb<4;bb++) {
        const int colw = wn*64 + bb*16 + l15;
        const float bi = biasp[colw];
        const size_t cbase = (size_t)(row0b + wm*32 + a*16 + 4*g)*DIM + col0 + colw;
        #pragma unroll
        for (int r=0;r<4;r++)
          Cout[cbase + (size_t)r*DIM] = (__bf16)(acc[a][bb][r] + bi);
      }
    }
  }
}

// ---------------- per-window attention (round-6 version, known-good) --------
__global__ __launch_bounds__(256) void k_attn(
    __bf16* qao,   // Q in, attn_out out (ALIASED — intentionally not restrict)
    const __bf16* __restrict__ Kws, const __bf16* __restrict__ Vws,
    const float* __restrict__ bias_pad)
{
  __shared__ __align__(16) __bf16 Psh[4][64*PSTR];
  __shared__ __align__(16) __bf16 VTsh[4][32*PSTR];
  int b = blockIdx.x;
  int lane = threadIdx.x & 63, wave = threadIdx.x >> 6;
  int l15 = lane & 15, g = lane >> 4;
  __bf16* Pw  = Psh[wave];
  __bf16* VTw = VTsh[wave];
  size_t rowbase = (size_t)b * NTOK * DIM;
  const float scale = 0.17677669529663687f;  // 32^-0.5

  for (int e = lane; e < 32*15; e += 64) {
    int d = e / 15, k = 49 + (e - d*15);
    VTw[d*PSTR + k] = (__bf16)0.0f;
  }

  for (int hh = 0; hh < 3; hh++) {
    int h = wave + hh*4;
    for (int e = lane; e < NTOK*HD; e += 64) {
      int k = e >> 5, d = e & 31;
      VTw[d*PSTR + k] = Vws[rowbase + (size_t)k*DIM + h*HD + d];
    }
    bf16x8 qf[4], kf[4];
    #pragma unroll
    for (int mt=0; mt<4; mt++) {
      int q = 16*mt + l15; if (q > 48) q = 48;
      qf[mt] = *(const bf16x8*)(qao + rowbase + (size_t)q*DIM + h*HD + g*8);
    }
    #pragma unroll
    for (int nt=0; nt<4; nt++) {
      int kk = 16*nt + l15; if (kk > 48) kk = 48;
      kf[nt] = *(const bf16x8*)(Kws + rowbase + (size_t)kk*DIM + h*HD + g*8);
    }
    f32x4 sacc[4][4];
    #pragma unroll
    for (int mt=0; mt<4; mt++)
      #pragma unroll
      for (int nt=0; nt<4; nt++)
        sacc[mt][nt] = mfma16(qf[mt], kf[nt], (f32x4){0.f,0.f,0.f,0.f});

    const float* bt = bias_pad + h*4096;
    float rs[4][4];
    #pragma unroll
    for (int mt=0; mt<4; mt++) {
      #pragma unroll
      for (int r=0; r<4; r++) {
        int q = 16*mt + 4*g + r;
        float v0 = sacc[mt][0][r]*scale + bt[q*64 +  0 + l15];
        float v1 = sacc[mt][1][r]*scale + bt[q*64 + 16 + l15];
        float v2 = sacc[mt][2][r]*scale + bt[q*64 + 32 + l15];
        float v3 = sacc[mt][3][r]*scale + bt[q*64 + 48 + l15];
        float m = fmaxf(fmaxf(v0,v1), fmaxf(v2,v3));
        #pragma unroll
        for (int off=1; off<16; off<<=1) m = fmaxf(m, __shfl_xor(m, off));
        v0 = __expf(v0-m); v1 = __expf(v1-m); v2 = __expf(v2-m); v3 = __expf(v3-m);
        float s = v0+v1+v2+v3;
        #pragma unroll
        for (int off=1; off<16; off<<=1) s += __shfl_xor(s, off);
        rs[mt][r] = s;
        Pw[q*PSTR +  0 + l15] = (__bf16)v0;
        Pw[q*PSTR + 16 + l15] = (__bf16)v1;
        Pw[q*PSTR + 32 + l15] = (__bf16)v2;
        Pw[q*PSTR + 48 + l15] = (__bf16)v3;
      }
    }

    #pragma unroll
    for (int mt=0; mt<4; mt++) {
      #pragma unroll
      for (int dt=0; dt<2; dt++) {
        f32x4 o = (f32x4){0.f,0.f,0.f,0.f};
        #pragma unroll
        for (int ks=0; ks<2; ks++) {
          bf16x8 pa = *(const bf16x8*)(Pw  + (16*mt + l15)*PSTR + 32*ks + 8*g);
          bf16x8 vb = *(const bf16x8*)(VTw + (16*dt + l15)*PSTR + 32*ks + 8*g);
          o = mfma16(pa, vb, o);
        }
        #pragma unroll
        for (int r=0; r<4; r++) {
          int q = 16*mt + 4*g + r;
          if (q < NTOK)
            qao[rowbase + (size_t)q*DIM + h*HD + 16*dt + l15] = (__bf16)(o[r] / rs[mt][r]);
        }
      }
    }
  }
}

// ---------------- proj v2 (race-fixed): same handshake, A via async gload ---
__global__ __launch_bounds__(256, 2) void k_proj2(
    const __bf16* __restrict__ Aao, const __bf16* __restrict__ pw_bf,
    const float* __restrict__ pb, float* __restrict__ out)
{
  __shared__ __align__(16) __bf16 Asub[12*64*32];   // 48 KB
  __shared__ __align__(16) __bf16 Bs[3*128*32];     // 24 KB ring

  const int mtile = blockIdx.x;
  const int row0b = mtile * 64;
  const int t = threadIdx.x, lane = t & 63, wave = t >> 6;
  const int l15 = lane & 15, g = lane >> 4;
  const int wm = wave >> 1, wn = wave & 1;

  const int sr  = 2*(lane >> 3) + ((lane >> 2) & 1);
  const int scb = (lane & 3) ^ ((lane >> 3) & 3);

  // ---- A staging: 48 async gloads (12 per wave), sub-tiles wave*3..+3 ----
  {
    const __bf16* aj0 = Aao + (size_t)(row0b +  0 + sr)*DIM + scb*8;
    const __bf16* aj1 = Aao + (size_t)(row0b + 16 + sr)*DIM + scb*8;
    const __bf16* aj2 = Aao + (size_t)(row0b + 32 + sr)*DIM + scb*8;
    const __bf16* aj3 = Aao + (size_t)(row0b + 48 + sr)*DIM + scb*8;
    #pragma unroll
    for (int stl = 0; stl < 3; ++stl) {
      const int st = wave*3 + stl;
      gload_lds16(aj0 + st*32, (char*)Asub + st*4096 +    0);
      gload_lds16(aj1 + st*32, (char*)Asub + st*4096 + 1024);
      gload_lds16(aj2 + st*32, (char*)Asub + st*4096 + 2048);
      gload_lds16(aj3 + st*32, (char*)Asub + st*4096 + 3072);
    }
  }

  const __bf16* bsrc0 = pw_bf + (size_t)((wave*2    )*16 + sr)*DIM + scb*8;
  const __bf16* bsrc1 = pw_bf + (size_t)((wave*2 + 1)*16 + sr)*DIM + scb*8;
  gload_lds16(bsrc0,      (char*)Bs        + (wave*2  )*1024);
  gload_lds16(bsrc1,      (char*)Bs        + (wave*2+1)*1024);
  gload_lds16(bsrc0 + 32, (char*)Bs + 8192 + (wave*2  )*1024);
  gload_lds16(bsrc1 + 32, (char*)Bs + 8192 + (wave*2+1)*1024);
  asm volatile("s_waitcnt vmcnt(4)" ::: "memory");   // my 12 A-gloads landed
  __builtin_amdgcn_s_barrier();                      // everyone's A landed

  const int lslot = l15*64 + ((g ^ ((l15 >> 1) & 3)) << 4);

  for (int jn = 0; jn < 3; ++jn) {
    const size_t co = (size_t)jn * 49152;
    const size_t cn = co + 49152;
    f32x4 acc[2][4];
    #pragma unroll
    for (int a=0;a<2;a++)
      #pragma unroll
      for (int bb=0;bb<4;bb++) acc[a][bb] = (f32x4){0.f,0.f,0.f,0.f};

    #pragma unroll
    for (int kt = 0; kt < 12; ++kt) {
      if (kt == 11 && jn == 2) asm volatile("s_waitcnt vmcnt(0)" ::: "memory");
      else                     asm volatile("s_waitcnt vmcnt(2)" ::: "memory");
      __builtin_amdgcn_s_barrier();

      const int cb = kt % 3;
      bf16x8 af[2], bfv[4];
      af[0] = *(const bf16x8*)((const char*)Asub + kt*4096 + (wm*32     )*64 + lslot);
      af[1] = *(const bf16x8*)((const char*)Asub + kt*4096 + (wm*32 + 16)*64 + lslot);
      #pragma unroll
      for (int bb=0;bb<4;bb++)
        bfv[bb] = *(const bf16x8*)((const char*)Bs + cb*8192 + (wn*64 + bb*16)*64 + lslot);

      if (kt < 10) {
        gload_lds16(bsrc0 + co + (kt+2)*32, (char*)Bs + ((kt+2)%3)*8192 + (wave*2  )*1024);
        gload_lds16(bsrc1 + co + (kt+2)*32, (char*)Bs + ((kt+2)%3)*8192 + (wave*2+1)*1024);
      } else if (jn < 2) {
        const int k2 = kt - 10;
        gload_lds16(bsrc0 + cn + k2*32, (char*)Bs + ((kt+2)%3)*8192 + (wave*2  )*1024);
        gload_lds16(bsrc1 + cn + k2*32, (char*)Bs + ((kt+2)%3)*8192 + (wave*2+1)*1024);
      }

      #pragma unroll
      for (int a=0;a<2;a++)
        #pragma unroll
        for (int bb=0;bb<4;bb++)
          acc[a][bb] = mfma16(af[a], bfv[bb], acc[a][bb]);
    }

    #pragma unroll
    for (int a=0;a<2;a++) {
      #pragma unroll
      for (int bb=0;bb<4;bb++) {
        const int col = jn*128 + wn*64 + bb*16 + l15;
        const float bi = pb[col];
        const size_t cbase = (size_t)(row0b + wm*32 + a*16 + 4*g)*DIM + col;
        #pragma unroll
        for (int r=0;r<4;r++)
          out[cbase + (size_t)r*DIM] = acc[a][bb][r] + bi;
      }
    }
  }
}

extern "C" void kernel_launch(void* const* d_in, const int* in_sizes, int n_in,
                              void* d_out, int out_size, void* d_ws, size_t ws_size,
                              hipStream_t stream)
{
  const float* x   = (const float*)d_in[0];
  const float* y   = (const float*)d_in[1];
  const float* qw  = (const float*)d_in[2];
  const float* qb  = (const float*)d_in[3];
  const float* kvw = (const float*)d_in[4];
  const float* kvb = (const float*)d_in[5];
  const float* pw  = (const float*)d_in[6];
  const float* pb  = (const float*)d_in[7];
  const float* rt  = (const float*)d_in[8];
  const int*   ri  = (const int*)d_in[9];
  float* out = (float*)d_out;

  char* ws = (char*)d_ws;
  const size_t WS_NEEDED = 1376256ull + 3ull*154140672ull;
  if (ws_size < WS_NEEDED) return;

  __bf16* qw_bf    = (__bf16*)(ws);
  __bf16* kvw_bf   = (__bf16*)(ws + 294912);
  __bf16* pw_bf    = (__bf16*)(ws + 884736);
  float*  bias_pad = (float*)(ws + 1179648);
  __bf16* Qws      = (__bf16*)(ws + 1376256);
  __bf16* Kws      = Qws + (size_t)MTOT*DIM;
  __bf16* Vws      = Kws + (size_t)MTOT*DIM;

  k_prep <<<dim3(1152), dim3(256), 0, stream>>>(qw, kvw, pw, rt, ri, qw_bf, kvw_bf, pw_bf, bias_pad);
  k_qkv2 <<<dim3(2*3136), dim3(256), 0, stream>>>(x, y, qw_bf, kvw_bf, qb, kvb, Qws, Kws, Vws);
  k_attn <<<dim3(NWIN), dim3(256), 0, stream>>>(Qws, Kws, Vws, bias_pad);
  k_proj2<<<dim3(3136), dim3(256), 0, stream>>>(Qws, pw_bf, pb, out);
}

// Round 14
// 865.761 us; speedup vs baseline: 1.0410x; 1.0410x over previous
//
#include <hip/hip_runtime.h>

#define DIM 384
#define HEADS 12
#define HD 32
#define NTOK 49
#define NWIN 4096
#define MTOT (NWIN*NTOK)   // 200704 = 1568 * 128
#define PSTR 72            // padded LDS row stride (elements) for P and V^T

typedef __attribute__((ext_vector_type(8))) __bf16 bf16x8;
typedef __attribute__((ext_vector_type(4))) __bf16 bf16x4;
typedef __attribute__((ext_vector_type(4))) float f32x4;

static __device__ __forceinline__ f32x4 mfma16(bf16x8 a, bf16x8 b, f32x4 c) {
  return __builtin_amdgcn_mfma_f32_16x16x32_bf16(a, b, c, 0, 0, 0);
}

// async global->LDS, 16B per lane: dest = lds_base(wave-uniform) + lane*16
static __device__ __forceinline__ void gload_lds16(const void* g, void* l) {
  __builtin_amdgcn_global_load_lds(
      (const __attribute__((address_space(1))) unsigned int*)g,
      (__attribute__((address_space(3))) unsigned int*)l, 16, 0, 0);
}

static __device__ __forceinline__ bf16x4 cvt4(float4 v) {
  bf16x4 t;
  t[0]=(__bf16)v.x; t[1]=(__bf16)v.y; t[2]=(__bf16)v.z; t[3]=(__bf16)v.w;
  return t;
}

// ---------------- prep: weights -> bf16, bias table expand ----------------
__global__ void k_prep(const float* __restrict__ qw, const float* __restrict__ kvw,
                       const float* __restrict__ pw, const float* __restrict__ rel_table,
                       const int* __restrict__ rel_index,
                       __bf16* __restrict__ qw_bf, __bf16* __restrict__ kvw_bf,
                       __bf16* __restrict__ pw_bf, float* __restrict__ bias_pad) {
  int i = blockIdx.x * 256 + threadIdx.x;
  if (i < DIM*DIM)   qw_bf[i] = (__bf16)qw[i];
  if (i < 2*DIM*DIM) kvw_bf[i] = (__bf16)kvw[i];
  if (i < DIM*DIM)   pw_bf[i] = (__bf16)pw[i];
  if (i < HEADS*64*64) {
    int h = i >> 12, rem = i & 4095, q = rem >> 6, k = rem & 63;
    float v;
    if (k >= NTOK)      v = -1e30f;   // key padding: masks softmax for free
    else if (q >= NTOK) v = 0.0f;     // query padding rows are discarded
    else v = rel_table[rel_index[q*NTOK + k] * HEADS + h];
    bias_pad[i] = v;
  }
}

// ---------------- fused QKV GEMM (round-6 core; Q pre-scaled by 32^-0.5) ----
__global__ __launch_bounds__(256, 4) void k_qkv(
    const float* __restrict__ x, const float* __restrict__ y,
    const __bf16* __restrict__ qw_bf, const __bf16* __restrict__ kvw_bf,
    const float* __restrict__ q_b, const float* __restrict__ kv_b,
    __bf16* __restrict__ Qws, __bf16* __restrict__ Kws, __bf16* __restrict__ Vws)
{
  // 14112 = 8 * 1764 : bijective XCD swizzle
  int b = blockIdx.x;
  int orig = (b & 7) * 1764 + (b >> 3);
  int mtile = orig / 9;
  int nt9 = orig - mtile*9;
  const float* A; const __bf16* Bw; const float* bias; __bf16* Cout;
  int wrow0, col0;
  if (nt9 < 3) { A = x; Bw = qw_bf; bias = q_b; Cout = Qws; wrow0 = nt9*128; col0 = wrow0; }
  else {
    A = y; Bw = kvw_bf; bias = kv_b; wrow0 = (nt9-3)*128;
    if (wrow0 < DIM) { Cout = Kws; col0 = wrow0; } else { Cout = Vws; col0 = wrow0 - DIM; }
  }
  bias += wrow0;
  // Q is pre-scaled here so k_attn's softmax input is just QK^T + bias
  const float osc = (nt9 < 3) ? 0.17677669529663687f : 1.0f;

  __shared__ __align__(16) __bf16 As[2*128*32];   // 2 x 8 KB (double buffer)
  __shared__ __align__(16) __bf16 Bs[3*128*32];   // 3 x 8 KB (ring, 2-deep prefetch)

  int t = threadIdx.x, lane = t & 63, wave = t >> 6;
  int l15 = lane & 15, g = lane >> 4;
  int wr = (wave >> 1) * 64, wc = (wave & 1) * 64;
  int row0b = mtile*128;

  int c8 = lane & 7;
  int r8 = lane >> 3;
  int swk = (lane >> 4) & 3;
  const float* asrc = A + (size_t)(row0b + wave*32 + r8)*DIM + c8*4;
  unsigned lwb = (unsigned)wave*2048 + (unsigned)r8*64
               + ((((c8 >> 1) ^ swk) << 4) + (c8 & 1)*8);

  int sr  = 2*(lane >> 3) + ((lane >> 2) & 1);
  int scb = (lane & 3) ^ ((lane >> 3) & 3);
  const __bf16* bsrc0 = Bw + (size_t)(wrow0 + (wave*2    )*16 + sr)*DIM + scb*8;
  const __bf16* bsrc1 = Bw + (size_t)(wrow0 + (wave*2 + 1)*16 + sr)*DIM + scb*8;

  f32x4 acc[4][4];
  #pragma unroll
  for (int a=0;a<4;a++)
    #pragma unroll
    for (int bb=0;bb<4;bb++) acc[a][bb] = (f32x4){0.f,0.f,0.f,0.f};

  {
    float4 s0 = *(const float4*)(asrc);
    float4 s1 = *(const float4*)(asrc +  8*DIM);
    float4 s2 = *(const float4*)(asrc + 16*DIM);
    float4 s3 = *(const float4*)(asrc + 24*DIM);
    gload_lds16(bsrc0,      (char*)Bs +        (wave*2  )*1024);
    gload_lds16(bsrc1,      (char*)Bs +        (wave*2+1)*1024);
    gload_lds16(bsrc0 + 32, (char*)Bs + 8192 + (wave*2  )*1024);
    gload_lds16(bsrc1 + 32, (char*)Bs + 8192 + (wave*2+1)*1024);
    *(bf16x4*)((char*)As + lwb +    0) = cvt4(s0);
    *(bf16x4*)((char*)As + lwb +  512) = cvt4(s1);
    *(bf16x4*)((char*)As + lwb + 1024) = cvt4(s2);
    *(bf16x4*)((char*)As + lwb + 1536) = cvt4(s3);
    asm volatile("s_waitcnt vmcnt(2)" ::: "memory");
    asm volatile("s_waitcnt lgkmcnt(0)" ::: "memory");
    __builtin_amdgcn_s_barrier();
  }

  int lslot = l15*64 + ((g ^ ((l15 >> 1) & 3)) << 4);

  #pragma unroll
  for (int kt = 0; kt < 12; ++kt) {
    const int cur2 = kt & 1, nxt2 = cur2 ^ 1;
    const int cur3 = kt % 3, pre3 = (kt + 2) % 3;
    float4 s0, s1, s2, s3;
    if (kt < 11) {
      int kk = (kt + 1) * 32;
      s0 = *(const float4*)(asrc + kk);
      s1 = *(const float4*)(asrc + kk +  8*DIM);
      s2 = *(const float4*)(asrc + kk + 16*DIM);
      s3 = *(const float4*)(asrc + kk + 24*DIM);
    }
    if (kt < 10) {
      int kk = (kt + 2) * 32;
      gload_lds16(bsrc0 + kk, (char*)Bs + pre3*8192 + (wave*2  )*1024);
      gload_lds16(bsrc1 + kk, (char*)Bs + pre3*8192 + (wave*2+1)*1024);
    }
    bf16x8 af[4], bfv[4];
    #pragma unroll
    for (int a=0;a<4;a++)
      af[a]  = *(const bf16x8*)((const char*)As + cur2*8192 + (wr + a*16)*64 + lslot);
    #pragma unroll
    for (int bb=0;bb<4;bb++)
      bfv[bb] = *(const bf16x8*)((const char*)Bs + cur3*8192 + (wc + bb*16)*64 + lslot);
    #pragma unroll
    for (int a=0;a<4;a++)
      #pragma unroll
      for (int bb=0;bb<4;bb++)
        acc[a][bb] = mfma16(af[a], bfv[bb], acc[a][bb]);
    if (kt < 11) {
      *(bf16x4*)((char*)As + nxt2*8192 + lwb +    0) = cvt4(s0);
      *(bf16x4*)((char*)As + nxt2*8192 + lwb +  512) = cvt4(s1);
      *(bf16x4*)((char*)As + nxt2*8192 + lwb + 1024) = cvt4(s2);
      *(bf16x4*)((char*)As + nxt2*8192 + lwb + 1536) = cvt4(s3);
      if (kt < 10) asm volatile("s_waitcnt vmcnt(2)" ::: "memory");
      else         asm volatile("s_waitcnt vmcnt(0)" ::: "memory");
      asm volatile("s_waitcnt lgkmcnt(0)" ::: "memory");
      __builtin_amdgcn_s_barrier();
    }
  }

  #pragma unroll
  for (int a=0;a<4;a++) {
    #pragma unroll
    for (int bb=0;bb<4;bb++) {
      int colw = wc + bb*16 + l15;
      float bi = bias[colw];
      size_t cbase = (size_t)(row0b + wr + a*16 + 4*g)*DIM + (col0 + colw);
      #pragma unroll
      for (int r=0;r<4;r++)
        Cout[cbase + (size_t)r*DIM] = (__bf16)((acc[a][bb][r] + bi) * osc);
    }
  }
}

// ---------------- per-window attention: 1-wave blocks (occupancy 2->11/CU) --
// Body identical to round-6 k_attn's per-wave work; block = one wave owning
// 3 heads of one window. No barriers, wave-private LDS (13.8 KB/block).
// Q arrives pre-scaled, so softmax input = sacc + bias (no mul).
__global__ __launch_bounds__(64) void k_attn(
    __bf16* qao,   // Q in, attn_out out (ALIASED — intentionally not restrict)
    const __bf16* __restrict__ Kws, const __bf16* __restrict__ Vws,
    const float* __restrict__ bias_pad)
{
  __shared__ __align__(16) __bf16 Pw[64*PSTR];    // 9216 B
  __shared__ __align__(16) __bf16 VTw[32*PSTR];   // 4608 B
  int bid = blockIdx.x;
  int b = bid >> 2;          // window
  int hq = bid & 3;          // head group (was: wave)
  int lane = threadIdx.x;
  int l15 = lane & 15, g = lane >> 4;
  size_t rowbase = (size_t)b * NTOK * DIM;

  // zero V^T pad columns k in [49,64) so pad contributes exact 0
  for (int e = lane; e < 32*15; e += 64) {
    int d = e / 15, k = 49 + (e - d*15);
    VTw[d*PSTR + k] = (__bf16)0.0f;
  }

  for (int hh = 0; hh < 3; hh++) {
    int h = hq + hh*4;
    for (int e = lane; e < NTOK*HD; e += 64) {
      int k = e >> 5, d = e & 31;
      VTw[d*PSTR + k] = Vws[rowbase + (size_t)k*DIM + h*HD + d];
    }
    bf16x8 qf[4], kf[4];
    #pragma unroll
    for (int mt=0; mt<4; mt++) {
      int q = 16*mt + l15; if (q > 48) q = 48;
      qf[mt] = *(const bf16x8*)(qao + rowbase + (size_t)q*DIM + h*HD + g*8);
    }
    #pragma unroll
    for (int nt=0; nt<4; nt++) {
      int kk = 16*nt + l15; if (kk > 48) kk = 48;
      kf[nt] = *(const bf16x8*)(Kws + rowbase + (size_t)kk*DIM + h*HD + g*8);
    }
    f32x4 sacc[4][4];
    #pragma unroll
    for (int mt=0; mt<4; mt++)
      #pragma unroll
      for (int nt=0; nt<4; nt++)
        sacc[mt][nt] = mfma16(qf[mt], kf[nt], (f32x4){0.f,0.f,0.f,0.f});

    const float* bt = bias_pad + h*4096;
    float rs[4][4];
    #pragma unroll
    for (int mt=0; mt<4; mt++) {
      #pragma unroll
      for (int r=0; r<4; r++) {
        int q = 16*mt + 4*g + r;
        float v0 = sacc[mt][0][r] + bt[q*64 +  0 + l15];
        float v1 = sacc[mt][1][r] + bt[q*64 + 16 + l15];
        float v2 = sacc[mt][2][r] + bt[q*64 + 32 + l15];
        float v3 = sacc[mt][3][r] + bt[q*64 + 48 + l15];
        float m = fmaxf(fmaxf(v0,v1), fmaxf(v2,v3));
        #pragma unroll
        for (int off=1; off<16; off<<=1) m = fmaxf(m, __shfl_xor(m, off));
        v0 = __expf(v0-m); v1 = __expf(v1-m); v2 = __expf(v2-m); v3 = __expf(v3-m);
        float s = v0+v1+v2+v3;
        #pragma unroll
        for (int off=1; off<16; off<<=1) s += __shfl_xor(s, off);
        rs[mt][r] = __frcp_rn(s);
        Pw[q*PSTR +  0 + l15] = (__bf16)v0;
        Pw[q*PSTR + 16 + l15] = (__bf16)v1;
        Pw[q*PSTR + 32 + l15] = (__bf16)v2;
        Pw[q*PSTR + 48 + l15] = (__bf16)v3;
      }
    }

    #pragma unroll
    for (int mt=0; mt<4; mt++) {
      #pragma unroll
      for (int dt=0; dt<2; dt++) {
        f32x4 o = (f32x4){0.f,0.f,0.f,0.f};
        #pragma unroll
        for (int ks=0; ks<2; ks++) {
          bf16x8 pa = *(const bf16x8*)(Pw  + (16*mt + l15)*PSTR + 32*ks + 8*g);
          bf16x8 vb = *(const bf16x8*)(VTw + (16*dt + l15)*PSTR + 32*ks + 8*g);
          o = mfma16(pa, vb, o);
        }
        #pragma unroll
        for (int r=0; r<4; r++) {
          int q = 16*mt + 4*g + r;
          if (q < NTOK)
            qao[rowbase + (size_t)q*DIM + h*HD + 16*dt + l15] = (__bf16)(o[r] * rs[mt][r]);
        }
      }
    }
  }
}

// ---------------- output projection (round-6 version, unchanged) -----------
__global__ __launch_bounds__(256, 4) void k_proj(
    const __bf16* __restrict__ Aao, const __bf16* __restrict__ pw_bf,
    const float* __restrict__ pb, float* __restrict__ out)
{
  // 4704 = 8 * 588 : bijective XCD swizzle
  int b = blockIdx.x;
  int orig = (b & 7) * 588 + (b >> 3);
  int mtile = orig / 3;
  int nt = orig - mtile*3;
  int lane = threadIdx.x & 63, wave = threadIdx.x >> 6;
  int l15 = lane & 15, g = lane >> 4;
  int wr = (wave >> 1) * 64, wc = (wave & 1) * 64;
  int row0b = mtile*128;
  int col00 = nt*128;

  __shared__ __align__(16) __bf16 As[3*128*32];   // 3 x 8 KB ring
  __shared__ __align__(16) __bf16 Bs[3*128*32];   // 3 x 8 KB ring

  int sr  = 2*(lane >> 3) + ((lane >> 2) & 1);
  int scb = (lane & 3) ^ ((lane >> 3) & 3);
  const __bf16* asrc0 = Aao   + (size_t)(row0b + (wave*2    )*16 + sr)*DIM + scb*8;
  const __bf16* asrc1 = Aao   + (size_t)(row0b + (wave*2 + 1)*16 + sr)*DIM + scb*8;
  const __bf16* bsrc0 = pw_bf + (size_t)(col00 + (wave*2    )*16 + sr)*DIM + scb*8;
  const __bf16* bsrc1 = pw_bf + (size_t)(col00 + (wave*2 + 1)*16 + sr)*DIM + scb*8;

  f32x4 acc[4][4];
  #pragma unroll
  for (int a=0;a<4;a++)
    #pragma unroll
    for (int bb=0;bb<4;bb++) acc[a][bb] = (f32x4){0.f,0.f,0.f,0.f};

  {
    gload_lds16(asrc0,      (char*)As +        (wave*2  )*1024);
    gload_lds16(asrc1,      (char*)As +        (wave*2+1)*1024);
    gload_lds16(bsrc0,      (char*)Bs +        (wave*2  )*1024);
    gload_lds16(bsrc1,      (char*)Bs +        (wave*2+1)*1024);
    gload_lds16(asrc0 + 32, (char*)As + 8192 + (wave*2  )*1024);
    gload_lds16(asrc1 + 32, (char*)As + 8192 + (wave*2+1)*1024);
    gload_lds16(bsrc0 + 32, (char*)Bs + 8192 + (wave*2  )*1024);
    gload_lds16(bsrc1 + 32, (char*)Bs + 8192 + (wave*2+1)*1024);
    asm volatile("s_waitcnt vmcnt(4)" ::: "memory");
    __builtin_amdgcn_s_barrier();
  }

  int lslot = l15*64 + ((g ^ ((l15 >> 1) & 3)) << 4);

  #pragma unroll
  for (int kt = 0; kt < 12; ++kt) {
    const int cur3 = kt % 3, pre3 = (kt + 2) % 3;
    if (kt < 10) {
      int kk = (kt + 2) * 32;
      gload_lds16(asrc0 + kk, (char*)As + pre3*8192 + (wave*2  )*1024);
      gload_lds16(asrc1 + kk, (char*)As + pre3*8192 + (wave*2+1)*1024);
      gload_lds16(bsrc0 + kk, (char*)Bs + pre3*8192 + (wave*2  )*1024);
      gload_lds16(bsrc1 + kk, (char*)Bs + pre3*8192 + (wave*2+1)*1024);
    }
    bf16x8 af[4], bfv[4];
    #pragma unroll
    for (int a=0;a<4;a++)
      af[a]  = *(const bf16x8*)((const char*)As + cur3*8192 + (wr + a*16)*64 + lslot);
    #pragma unroll
    for (int bb=0;bb<4;bb++)
      bfv[bb] = *(const bf16x8*)((const char*)Bs + cur3*8192 + (wc + bb*16)*64 + lslot);
    #pragma unroll
    for (int a=0;a<4;a++)
      #pragma unroll
      for (int bb=0;bb<4;bb++)
        acc[a][bb] = mfma16(af[a], bfv[bb], acc[a][bb]);
    if (kt < 11) {
      if (kt < 10) asm volatile("s_waitcnt vmcnt(4)" ::: "memory");
      else         asm volatile("s_waitcnt vmcnt(0)" ::: "memory");
      __builtin_amdgcn_s_barrier();
    }
  }

  #pragma unroll
  for (int a=0;a<4;a++) {
    #pragma unroll
    for (int bb=0;bb<4;bb++) {
      int col = col00 + wc + bb*16 + l15;
      float bi = pb[col];
      size_t cbase = (size_t)(row0b + wr + a*16 + 4*g)*DIM + col;
      #pragma unroll
      for (int r=0;r<4;r++)
        out[cbase + (size_t)r*DIM] = acc[a][bb][r] + bi;
    }
  }
}

extern "C" void kernel_launch(void* const* d_in, const int* in_sizes, int n_in,
                              void* d_out, int out_size, void* d_ws, size_t ws_size,
                              hipStream_t stream)
{
  const float* x   = (const float*)d_in[0];
  const float* y   = (const float*)d_in[1];
  const float* qw  = (const float*)d_in[2];
  const float* qb  = (const float*)d_in[3];
  const float* kvw = (const float*)d_in[4];
  const float* kvb = (const float*)d_in[5];
  const float* pw  = (const float*)d_in[6];
  const float* pb  = (const float*)d_in[7];
  const float* rt  = (const float*)d_in[8];
  const int*   ri  = (const int*)d_in[9];
  float* out = (float*)d_out;

  char* ws = (char*)d_ws;
  const size_t WS_NEEDED = 1376256ull + 3ull*154140672ull;
  if (ws_size < WS_NEEDED) return;

  __bf16* qw_bf    = (__bf16*)(ws);
  __bf16* kvw_bf   = (__bf16*)(ws + 294912);
  __bf16* pw_bf    = (__bf16*)(ws + 884736);
  float*  bias_pad = (float*)(ws + 1179648);
  __bf16* Qws      = (__bf16*)(ws + 1376256);
  __bf16* Kws      = Qws + (size_t)MTOT*DIM;
  __bf16* Vws      = Kws + (size_t)MTOT*DIM;

  k_prep<<<dim3(1152), dim3(256), 0, stream>>>(qw, kvw, pw, rt, ri, qw_bf, kvw_bf, pw_bf, bias_pad);
  k_qkv <<<dim3(1568*9), dim3(256), 0, stream>>>(x, y, qw_bf, kvw_bf, qb, kvb, Qws, Kws, Vws);
  k_attn<<<dim3(NWIN*4), dim3(64), 0, stream>>>(Qws, Kws, Vws, bias_pad);
  k_proj<<<dim3(1568*3), dim3(256), 0, stream>>>(Qws, pw_bf, pb, out);
}